// Round 27
// baseline (134.302 us; speedup 1.0000x reference)
//
#include <hip/hip_runtime.h>
#include <hip/hip_bf16.h>
#include <hip/hip_fp16.h>

#define N_NODES 50000
#define N_EDGES 800000
#define IN_F 256
#define NH 4
#define DH 64
#define HD 256
#define ALPHA 0.2f
#define EPB 16384                                  // edges per hist block (2^14)
#define NHB ((N_EDGES + EPB - 1) / EPB)            // 49 hist blocks / copies
#define GEMMB ((N_NODES + 255) / 256)              // 196 gemm blocks (BM=256)
#define SCATB ((N_EDGES / 8 + 511) / 512)          // 196 scatter blocks

typedef short bf16x8 __attribute__((ext_vector_type(8)));
typedef float f32x4 __attribute__((ext_vector_type(4)));

__device__ __forceinline__ unsigned short f2bf(float f) {
    unsigned u = __float_as_uint(f);
    u = (u + 0x7FFFu + ((u >> 16) & 1u)) >> 16;   // RNE
    return (unsigned short)u;
}

// ---------------- PRE: hist (0..48) | Bt cvt (49..176) ----------------
__global__ __launch_bounds__(512) void k_pre(const float* __restrict__ fw,
                                             unsigned short* __restrict__ Bt,
                                             const int* __restrict__ dst,
                                             unsigned short* __restrict__ hist16,
                                             unsigned short* __restrict__ erank16,
                                             int* __restrict__ gcursor) {
    __shared__ int cnt[N_NODES / 2];               // 100 KB (hist blocks only)
    const int tid = threadIdx.x;

    if (blockIdx.x >= NHB) {
        // -------- Bt convert block --------
        if (blockIdx.x == NHB && tid == 0) *gcursor = 0;
        int t = (blockIdx.x - NHB) * 512 + tid;    // 0..65535
        int n = t >> 8, k = t & 255;
        Bt[n * 256 + k] = f2bf(fw[k * 256 + n]);
        return;
    }

    // -------- histogram block --------
    const int b = blockIdx.x;
    for (int i = tid; i < N_NODES / 2; i += 512) cnt[i] = 0;
    __syncthreads();
    const int e0 = b * EPB;
    const int eend = min(e0 + EPB, N_EDGES);
    for (int e = e0 + tid; e < eend; e += 512) {
        int d = dst[e];
        int old = atomicAdd(&cnt[d >> 1], (d & 1) ? (1 << 16) : 1);
        erank16[e] = (unsigned short)((d & 1) ? ((old >> 16) & 0xffff) : (old & 0xffff));
    }
    __syncthreads();
    int4* hb = (int4*)(hist16 + (size_t)b * N_NODES);
    for (int i = tid; i < N_NODES / 8; i += 512)
        hb[i] = ((const int4*)cnt)[i];
}

// ---------------- fused scan: per-copy u16 prefixes + unordered segment alloc ----
__global__ __launch_bounds__(512) void k_scan(unsigned short* __restrict__ hist16,
                                              int* __restrict__ counts,
                                              int* __restrict__ offs,
                                              int* __restrict__ gcursor, int N) {
    __shared__ int sm[512];
    __shared__ int sbase;
    int i = blockIdx.x * 512 + threadIdx.x;
    int v = 0;
    if (i < N) {
        int pf = 0;
        for (int c = 0; c < NHB; c++) {
            unsigned short* p = hist16 + (size_t)c * N_NODES + i;
            int t = *p;
            *p = (unsigned short)pf;
            pf += t;
        }
        v = pf;
        counts[i] = v;
    }
    sm[threadIdx.x] = v;
    __syncthreads();
    for (int off = 1; off < 512; off <<= 1) {
        int t = (threadIdx.x >= off) ? sm[threadIdx.x - off] : 0;
        __syncthreads();
        sm[threadIdx.x] += t;
        __syncthreads();
    }
    if (threadIdx.x == 511) sbase = atomicAdd(gcursor, sm[511]);
    __syncthreads();
    if (i < N) offs[i] = sbase + sm[threadIdx.x] - v;
}

// ---------------- MAIN: blocks 0..195 = GEMM (A staged fp32->bf16 in LDS, B from L2),
//                  blocks 196..391 = scatter. 64 KB LDS -> 2 blocks/CU, co-resident.
__global__ __launch_bounds__(512) void k_main(const float* __restrict__ feat,
                                              const unsigned short* __restrict__ Bt,
                                              unsigned short* __restrict__ fth,
                                              float* __restrict__ el,
                                              float* __restrict__ er,
                                              const float* __restrict__ al,
                                              const float* __restrict__ ar,
                                              const int* __restrict__ src,
                                              const int* __restrict__ dst,
                                              const unsigned short* __restrict__ hist16,
                                              const int* __restrict__ offs,
                                              const unsigned short* __restrict__ erank16,
                                              int* __restrict__ esrc, int M) {
    __shared__ __align__(16) char smem[65536];     // A half-tile: 256 rows x 128 k bf16
    const int tid = threadIdx.x;

    if (blockIdx.x >= GEMMB) {
        // -------- scatter block: 8 edges/thread, one pass --------
        int t = (blockIdx.x - GEMMB) * 512 + tid;
        if (t < N_EDGES / 8) {
            int e = t * 8;
            const unsigned short* hp = hist16 + (size_t)(e >> 14) * N_NODES;
            int4 da = *(const int4*)(dst + e);
            int4 db = *(const int4*)(dst + e + 4);
            int4 sa = *(const int4*)(src + e);
            int4 sb = *(const int4*)(src + e + 4);
            ushort4 ra = *(const ushort4*)(erank16 + e);
            ushort4 rb = *(const ushort4*)(erank16 + e + 4);
            esrc[hp[da.x] + offs[da.x] + ra.x] = sa.x;
            esrc[hp[da.y] + offs[da.y] + ra.y] = sa.y;
            esrc[hp[da.z] + offs[da.z] + ra.z] = sa.z;
            esrc[hp[da.w] + offs[da.w] + ra.w] = sa.w;
            esrc[hp[db.x] + offs[db.x] + rb.x] = sb.x;
            esrc[hp[db.y] + offs[db.y] + rb.y] = sb.y;
            esrc[hp[db.z] + offs[db.z] + rb.z] = sb.z;
            esrc[hp[db.w] + offs[db.w] + rb.w] = sb.w;
        }
        return;
    }

    // -------- GEMM block --------
    const int m0 = blockIdx.x * 256;
    const int w = tid >> 6, lane = tid & 63;
    const int wm = w >> 2, wn = w & 3;          // 2 x 4; wave: 128 rows x 64 cols (head wn)
    const int fr = lane & 15, quad = lane >> 4;

    int gm[8];
    #pragma unroll
    for (int j = 0; j < 8; j++) gm[j] = m0 + wm * 128 + j * 16 + fr;

    f32x4 acc[8][4];
    #pragma unroll
    for (int j = 0; j < 8; j++)
        #pragma unroll
        for (int f = 0; f < 4; f++) acc[j][f] = (f32x4){0.f, 0.f, 0.f, 0.f};

    #pragma unroll
    for (int h = 0; h < 2; h++) {
        if (h) __syncthreads();                 // prior stage fully consumed
        // stage A rows m0..m0+255, k-elems [h*128, h*128+128): fp32 -> bf16, 64 KB
        #pragma unroll
        for (int c = 0; c < 8; c++) {
            int o = c * 8192 + tid * 16;        // bf16 byte offset in half-tile
            int row = o >> 8;                   // 0..255
            int kb = o & 255;                   // byte within 256-B bf16 half-row
            int grow = m0 + row; if (grow >= M) grow = M - 1;
            const float* sp = feat + (size_t)grow * IN_F + h * 128 + (kb >> 1);
            float4 lo = *(const float4*)sp;
            float4 hi = *(const float4*)(sp + 4);
            bf16x8 v;
            v[0] = (short)f2bf(lo.x); v[1] = (short)f2bf(lo.y);
            v[2] = (short)f2bf(lo.z); v[3] = (short)f2bf(lo.w);
            v[4] = (short)f2bf(hi.x); v[5] = (short)f2bf(hi.y);
            v[6] = (short)f2bf(hi.z); v[7] = (short)f2bf(hi.w);
            int lb = o ^ ((row & 7) << 4);
            *(bf16x8*)(smem + lb) = v;
        }
        __syncthreads();

        #pragma unroll
        for (int t = 0; t < 4; t++) {
            int kk = h * 4 + t;
            bf16x8 af[8];
            #pragma unroll
            for (int j = 0; j < 8; j++) {
                int row_a = wm * 128 + j * 16 + fr;
                int lb = (row_a * 256 + t * 64 + quad * 16) ^ ((row_a & 7) << 4);
                af[j] = *(const bf16x8*)(smem + lb);
            }
            #pragma unroll
            for (int f = 0; f < 4; f++) {
                int nl = wn * 64 + f * 16 + fr;
                bf16x8 bfr = *(const bf16x8*)((const char*)Bt + (size_t)nl * 512 + kk * 64 + quad * 16);
                #pragma unroll
                for (int j = 0; j < 8; j++)
                    acc[j][f] = __builtin_amdgcn_mfma_f32_16x16x32_bf16(bfr, af[j], acc[j][f], 0, 0, 0);
            }
        }
    }
    // lane holds D[row = m0+wm*128+j*16+fr][col = wn*64+f*16+quad*4+r]

    // fused el/er (head wn)
    #pragma unroll
    for (int j = 0; j < 8; j++) {
        float pl = 0.f, pr = 0.f;
        #pragma unroll
        for (int f = 0; f < 4; f++) {
            float4 a4 = *(const float4*)(al + wn * 64 + f * 16 + quad * 4);
            float4 b4 = *(const float4*)(ar + wn * 64 + f * 16 + quad * 4);
            pl += acc[j][f][0] * a4.x + acc[j][f][1] * a4.y + acc[j][f][2] * a4.z + acc[j][f][3] * a4.w;
            pr += acc[j][f][0] * b4.x + acc[j][f][1] * b4.y + acc[j][f][2] * b4.z + acc[j][f][3] * b4.w;
        }
        pl += __shfl_xor(pl, 16); pl += __shfl_xor(pl, 32);
        pr += __shfl_xor(pr, 16); pr += __shfl_xor(pr, 32);
        if (quad == 0 && gm[j] < M) {
            el[gm[j] * NH + wn] = pl;
            er[gm[j] * NH + wn] = pr;
        }
    }

    // direct f16 stores
    #pragma unroll
    for (int j = 0; j < 8; j++) {
        if (gm[j] < M) {
            unsigned short* dp = fth + (size_t)gm[j] * HD + wn * 64 + quad * 4;
            #pragma unroll
            for (int f = 0; f < 4; f++) {
                ushort4 pk;
                pk.x = __half_as_ushort(__float2half(acc[j][f][0]));
                pk.y = __half_as_ushort(__float2half(acc[j][f][1]));
                pk.z = __half_as_ushort(__float2half(acc[j][f][2]));
                pk.w = __half_as_ushort(__float2half(acc[j][f][3]));
                *(ushort4*)(dp + f * 16) = pk;
            }
        }
    }
}

// ---------------- Aggregation: one wave per dst node, SINGLE PASS ----------------
__global__ __launch_bounds__(256) void k_agg(const unsigned short* __restrict__ fth,
                                             const float* __restrict__ el,
                                             const float* __restrict__ er,
                                             const int* __restrict__ offs,
                                             const int* __restrict__ counts,
                                             const int* __restrict__ esrc,
                                             float* __restrict__ out, int N) {
    int wid = (blockIdx.x * 256 + threadIdx.x) >> 6;
    const int lane = threadIdx.x & 63;
    if (wid >= N) return;
    const int deg = counts[wid];
    const int start = offs[wid];
    const int quad = lane >> 4;                 // head of my 4 cols
    const float erq = er[wid * NH + quad];

    float s = 0.f;
    float a0 = 0.f, a1 = 0.f, a2 = 0.f, a3 = 0.f;
    #pragma unroll 4
    for (int i = 0; i < deg; i++) {
        int sv = esrc[start + i];                     // wave-uniform
        float x = el[sv * NH + quad] + erq;           // 1-line broadcast gather
        x = (x > 0.f) ? x : ALPHA * x;
        float wgt = __expf(x);
        s += wgt;
        float2 raw = ((const float2*)fth)[(size_t)sv * 64 + lane];
        __half2 h0 = *reinterpret_cast<const __half2*>(&raw.x);
        __half2 h1 = *reinterpret_cast<const __half2*>(&raw.y);
        a0 = fmaf(wgt, __low2float(h0), a0);
        a1 = fmaf(wgt, __high2float(h0), a1);
        a2 = fmaf(wgt, __low2float(h1), a2);
        a3 = fmaf(wgt, __high2float(h1), a3);
    }
    float invd = (deg > 0 && s > 0.f) ? 1.f / s : 0.f;
    f32x4 o;
    o[0] = a0 * invd; o[1] = a1 * invd; o[2] = a2 * invd; o[3] = a3 * invd;
    __builtin_nontemporal_store(o, (f32x4*)out + (size_t)wid * 64 + lane);
}

// ---------------- launch ----------------
extern "C" void kernel_launch(void* const* d_in, const int* in_sizes, int n_in,
                              void* d_out, int out_size, void* d_ws, size_t ws_size,
                              hipStream_t stream) {
    const float* feat = (const float*)d_in[0];
    const float* fc_w = (const float*)d_in[1];
    const float* attn_l = (const float*)d_in[2];
    const float* attn_r = (const float*)d_in[3];
    const int* src = (const int*)d_in[4];
    const int* dst = (const int*)d_in[5];
    float* out = (float*)d_out;

    char* w = (char*)d_ws;
    unsigned short* fth = (unsigned short*)w;  w += (size_t)N_NODES * HD * 2;      // 25.6 MB (f16)
    unsigned short* Bt = (unsigned short*)w;   w += (size_t)IN_F * HD * 2;         // 128 KB (bf16)
    float* el = (float*)w;       w += (size_t)N_NODES * NH * 4;                    // 800 KB
    float* er = (float*)w;       w += (size_t)N_NODES * NH * 4;                    // 800 KB
    unsigned short* hist16 = (unsigned short*)w;  w += (size_t)NHB * N_NODES * 2;  // 4.9 MB
    int* counts = (int*)w;       w += (size_t)N_NODES * 4;
    int* offs = (int*)w;         w += (size_t)N_NODES * 4;
    int* gcursor = (int*)w;      w += 256;
    unsigned short* erank16 = (unsigned short*)w; w += (size_t)N_EDGES * 2;        // 1.6 MB
    int* esrc = (int*)w;         w += (size_t)N_EDGES * 4;                          // 3.2 MB

    // pre: 49 hist + 128 Bt-cvt blocks (one dispatch)
    k_pre<<<NHB + 128, 512, 0, stream>>>(fc_w, Bt, dst, hist16, erank16, gcursor);

    k_scan<<<(N_NODES + 511) / 512, 512, 0, stream>>>(hist16, counts, offs,
                                                      gcursor, N_NODES);

    // main: 196 gemm (A staged fp32->bf16, 64 KB LDS) + 196 scatter, co-resident
    k_main<<<GEMMB + SCATB, 512, 0, stream>>>(feat, Bt, fth, el, er, attn_l, attn_r,
                                              src, dst, hist16, offs, erank16,
                                              esrc, N_NODES);

    int agg_blocks = (N_NODES * 64 + 255) / 256;
    k_agg<<<agg_blocks, 256, 0, stream>>>(fth, el, er, offs, counts, esrc, out, N_NODES);
}

// Round 28
// 129.323 us; speedup vs baseline: 1.0385x; 1.0385x over previous
//
#include <hip/hip_runtime.h>
#include <hip/hip_bf16.h>
#include <hip/hip_fp16.h>

#define N_NODES 50000
#define N_EDGES 800000
#define IN_F 256
#define NH 4
#define DH 64
#define HD 256
#define ALPHA 0.2f
#define EPB 16384                                  // edges per hist block (2^14)
#define NHB ((N_EDGES + EPB - 1) / EPB)            // 49 hist blocks / copies
#define GEMMB ((N_NODES + 255) / 256)              // 196 gemm blocks (BM=256)
#define SCATB ((N_EDGES / 8 + 511) / 512)          // 196 scatter blocks
#define FCVB (N_NODES * HD / 8 / 512)              // 3125 feat-cvt blocks

typedef short bf16x8 __attribute__((ext_vector_type(8)));
typedef float f32x4 __attribute__((ext_vector_type(4)));

__device__ __forceinline__ unsigned short f2bf(float f) {
    unsigned u = __float_as_uint(f);
    u = (u + 0x7FFFu + ((u >> 16) & 1u)) >> 16;   // RNE
    return (unsigned short)u;
}

// ---------------- PRE: hist (0..48) | Bt cvt (49..176) | feat cvt (177..3301) ----
__global__ __launch_bounds__(512) void k_pre(const float* __restrict__ fw,
                                             unsigned short* __restrict__ Bt,
                                             const float* __restrict__ feat,
                                             unsigned short* __restrict__ fb,
                                             const int* __restrict__ dst,
                                             unsigned short* __restrict__ hist16,
                                             unsigned short* __restrict__ erank16,
                                             int* __restrict__ gcursor) {
    __shared__ int cnt[N_NODES / 2];               // 100 KB (hist blocks only)
    const int tid = threadIdx.x;

    if (blockIdx.x >= NHB + 128) {
        // -------- feat convert block --------
        int t = (blockIdx.x - (NHB + 128)) * 512 + tid;   // < 1.6M
        const float* sp = feat + (size_t)t * 8;
        float4 lo = *(const float4*)sp;
        float4 hi = *(const float4*)(sp + 4);
        bf16x8 v;
        v[0] = (short)f2bf(lo.x); v[1] = (short)f2bf(lo.y);
        v[2] = (short)f2bf(lo.z); v[3] = (short)f2bf(lo.w);
        v[4] = (short)f2bf(hi.x); v[5] = (short)f2bf(hi.y);
        v[6] = (short)f2bf(hi.z); v[7] = (short)f2bf(hi.w);
        *(bf16x8*)(fb + (size_t)t * 8) = v;
        return;
    }

    if (blockIdx.x >= NHB) {
        // -------- Bt convert block --------
        if (blockIdx.x == NHB && tid == 0) *gcursor = 0;
        int t = (blockIdx.x - NHB) * 512 + tid;    // 0..65535
        int n = t >> 8, k = t & 255;
        Bt[n * 256 + k] = f2bf(fw[k * 256 + n]);
        return;
    }

    // -------- histogram block --------
    const int b = blockIdx.x;
    for (int i = tid; i < N_NODES / 2; i += 512) cnt[i] = 0;
    __syncthreads();
    const int e0 = b * EPB;
    const int eend = min(e0 + EPB, N_EDGES);
    for (int e = e0 + tid; e < eend; e += 512) {
        int d = dst[e];
        int old = atomicAdd(&cnt[d >> 1], (d & 1) ? (1 << 16) : 1);
        erank16[e] = (unsigned short)((d & 1) ? ((old >> 16) & 0xffff) : (old & 0xffff));
    }
    __syncthreads();
    int4* hb = (int4*)(hist16 + (size_t)b * N_NODES);
    for (int i = tid; i < N_NODES / 8; i += 512)
        hb[i] = ((const int4*)cnt)[i];
}

// ---------------- fused scan: per-copy u16 prefixes + unordered segment alloc ----
__global__ __launch_bounds__(512) void k_scan(unsigned short* __restrict__ hist16,
                                              int* __restrict__ counts,
                                              int* __restrict__ offs,
                                              int* __restrict__ gcursor, int N) {
    __shared__ int sm[512];
    __shared__ int sbase;
    int i = blockIdx.x * 512 + threadIdx.x;
    int v = 0;
    if (i < N) {
        int pf = 0;
        for (int c = 0; c < NHB; c++) {
            unsigned short* p = hist16 + (size_t)c * N_NODES + i;
            int t = *p;
            *p = (unsigned short)pf;
            pf += t;
        }
        v = pf;
        counts[i] = v;
    }
    sm[threadIdx.x] = v;
    __syncthreads();
    for (int off = 1; off < 512; off <<= 1) {
        int t = (threadIdx.x >= off) ? sm[threadIdx.x - off] : 0;
        __syncthreads();
        sm[threadIdx.x] += t;
        __syncthreads();
    }
    if (threadIdx.x == 511) sbase = atomicAdd(gcursor, sm[511]);
    __syncthreads();
    if (i < N) offs[i] = sbase + sm[threadIdx.x] - v;
}

// ---------------- MAIN: blocks 0..195 = GEMM (A in LDS, B from L2), 196.. = scatter
__global__ __launch_bounds__(512) void k_main(const unsigned short* __restrict__ fb,
                                              const unsigned short* __restrict__ Bt,
                                              unsigned short* __restrict__ fth,
                                              float* __restrict__ el,
                                              float* __restrict__ er,
                                              const float* __restrict__ al,
                                              const float* __restrict__ ar,
                                              const int* __restrict__ src,
                                              const int* __restrict__ dst,
                                              const unsigned short* __restrict__ hist16,
                                              const int* __restrict__ offs,
                                              const unsigned short* __restrict__ erank16,
                                              int* __restrict__ esrc, int M) {
    __shared__ __align__(16) char smem[65536];     // A half-tile: 256 rows x 128 k bf16
    const int tid = threadIdx.x;

    if (blockIdx.x >= GEMMB) {
        // -------- scatter block: 8 edges/thread, one pass --------
        int t = (blockIdx.x - GEMMB) * 512 + tid;
        if (t < N_EDGES / 8) {
            int e = t * 8;
            const unsigned short* hp = hist16 + (size_t)(e >> 14) * N_NODES;
            int4 da = *(const int4*)(dst + e);
            int4 db = *(const int4*)(dst + e + 4);
            int4 sa = *(const int4*)(src + e);
            int4 sb = *(const int4*)(src + e + 4);
            ushort4 ra = *(const ushort4*)(erank16 + e);
            ushort4 rb = *(const ushort4*)(erank16 + e + 4);
            esrc[hp[da.x] + offs[da.x] + ra.x] = sa.x;
            esrc[hp[da.y] + offs[da.y] + ra.y] = sa.y;
            esrc[hp[da.z] + offs[da.z] + ra.z] = sa.z;
            esrc[hp[da.w] + offs[da.w] + ra.w] = sa.w;
            esrc[hp[db.x] + offs[db.x] + rb.x] = sb.x;
            esrc[hp[db.y] + offs[db.y] + rb.y] = sb.y;
            esrc[hp[db.z] + offs[db.z] + rb.z] = sb.z;
            esrc[hp[db.w] + offs[db.w] + rb.w] = sb.w;
        }
        return;
    }

    // -------- GEMM block --------
    const int m0 = blockIdx.x * 256;
    const int w = tid >> 6, lane = tid & 63;
    const int wm = w >> 2, wn = w & 3;          // 2 x 4; wave: 128 rows x 64 cols (head wn)
    const int fr = lane & 15, quad = lane >> 4;

    int gm[8];
    #pragma unroll
    for (int j = 0; j < 8; j++) gm[j] = m0 + wm * 128 + j * 16 + fr;

    f32x4 acc[8][4];
    #pragma unroll
    for (int j = 0; j < 8; j++)
        #pragma unroll
        for (int f = 0; f < 4; f++) acc[j][f] = (f32x4){0.f, 0.f, 0.f, 0.f};

    #pragma unroll
    for (int h = 0; h < 2; h++) {
        if (h) __syncthreads();                 // prior stage fully consumed
        // stage A rows m0..m0+255, k-bytes [h*256, h*256+256): 64 KB, coalesced
        #pragma unroll
        for (int c = 0; c < 8; c++) {
            int o = c * 8192 + tid * 16;        // byte offset in half-tile
            int row = o >> 8;                   // 0..255
            int kb = o & 255;                   // byte within 256-B half-row
            bf16x8 v = *(const bf16x8*)((const char*)fb + (size_t)(m0 + row) * 512 + h * 256 + kb);
            int lb = o ^ ((row & 7) << 4);
            *(bf16x8*)(smem + lb) = v;
        }
        __syncthreads();

        #pragma unroll
        for (int t = 0; t < 4; t++) {
            int kk = h * 4 + t;
            bf16x8 af[8];
            #pragma unroll
            for (int j = 0; j < 8; j++) {
                int row_a = wm * 128 + j * 16 + fr;
                int lb = (row_a * 256 + t * 64 + quad * 16) ^ ((row_a & 7) << 4);
                af[j] = *(const bf16x8*)(smem + lb);
            }
            #pragma unroll
            for (int f = 0; f < 4; f++) {
                int nl = wn * 64 + f * 16 + fr;
                bf16x8 bfr = *(const bf16x8*)((const char*)Bt + (size_t)nl * 512 + kk * 64 + quad * 16);
                #pragma unroll
                for (int j = 0; j < 8; j++)
                    acc[j][f] = __builtin_amdgcn_mfma_f32_16x16x32_bf16(bfr, af[j], acc[j][f], 0, 0, 0);
            }
        }
    }
    // lane holds D[row = m0+wm*128+j*16+fr][col = wn*64+f*16+quad*4+r]

    // fused el/er (head wn)
    #pragma unroll
    for (int j = 0; j < 8; j++) {
        float pl = 0.f, pr = 0.f;
        #pragma unroll
        for (int f = 0; f < 4; f++) {
            float4 a4 = *(const float4*)(al + wn * 64 + f * 16 + quad * 4);
            float4 b4 = *(const float4*)(ar + wn * 64 + f * 16 + quad * 4);
            pl += acc[j][f][0] * a4.x + acc[j][f][1] * a4.y + acc[j][f][2] * a4.z + acc[j][f][3] * a4.w;
            pr += acc[j][f][0] * b4.x + acc[j][f][1] * b4.y + acc[j][f][2] * b4.z + acc[j][f][3] * b4.w;
        }
        pl += __shfl_xor(pl, 16); pl += __shfl_xor(pl, 32);
        pr += __shfl_xor(pr, 16); pr += __shfl_xor(pr, 32);
        if (quad == 0 && gm[j] < M) {
            el[gm[j] * NH + wn] = pl;
            er[gm[j] * NH + wn] = pr;
        }
    }

    // direct f16 stores
    #pragma unroll
    for (int j = 0; j < 8; j++) {
        if (gm[j] < M) {
            unsigned short* dp = fth + (size_t)gm[j] * HD + wn * 64 + quad * 4;
            #pragma unroll
            for (int f = 0; f < 4; f++) {
                ushort4 pk;
                pk.x = __half_as_ushort(__float2half(acc[j][f][0]));
                pk.y = __half_as_ushort(__float2half(acc[j][f][1]));
                pk.z = __half_as_ushort(__float2half(acc[j][f][2]));
                pk.w = __half_as_ushort(__float2half(acc[j][f][3]));
                *(ushort4*)(dp + f * 16) = pk;
            }
        }
    }
}

// ---------------- Aggregation: one wave per dst node, SINGLE PASS ----------------
__global__ __launch_bounds__(256) void k_agg(const unsigned short* __restrict__ fth,
                                             const float* __restrict__ el,
                                             const float* __restrict__ er,
                                             const int* __restrict__ offs,
                                             const int* __restrict__ counts,
                                             const int* __restrict__ esrc,
                                             float* __restrict__ out, int N) {
    int wid = (blockIdx.x * 256 + threadIdx.x) >> 6;
    const int lane = threadIdx.x & 63;
    if (wid >= N) return;
    const int deg = counts[wid];
    const int start = offs[wid];
    const int quad = lane >> 4;                 // head of my 4 cols
    const float erq = er[wid * NH + quad];

    float s = 0.f;
    float a0 = 0.f, a1 = 0.f, a2 = 0.f, a3 = 0.f;
    #pragma unroll 4
    for (int i = 0; i < deg; i++) {
        int sv = esrc[start + i];                     // wave-uniform
        float x = el[sv * NH + quad] + erq;           // 1-line broadcast gather
        x = (x > 0.f) ? x : ALPHA * x;
        float wgt = __expf(x);
        s += wgt;
        float2 raw = ((const float2*)fth)[(size_t)sv * 64 + lane];
        __half2 h0 = *reinterpret_cast<const __half2*>(&raw.x);
        __half2 h1 = *reinterpret_cast<const __half2*>(&raw.y);
        a0 = fmaf(wgt, __low2float(h0), a0);
        a1 = fmaf(wgt, __high2float(h0), a1);
        a2 = fmaf(wgt, __low2float(h1), a2);
        a3 = fmaf(wgt, __high2float(h1), a3);
    }
    float invd = (deg > 0 && s > 0.f) ? 1.f / s : 0.f;
    f32x4 o;
    o[0] = a0 * invd; o[1] = a1 * invd; o[2] = a2 * invd; o[3] = a3 * invd;
    __builtin_nontemporal_store(o, (f32x4*)out + (size_t)wid * 64 + lane);
}

// ---------------- launch ----------------
extern "C" void kernel_launch(void* const* d_in, const int* in_sizes, int n_in,
                              void* d_out, int out_size, void* d_ws, size_t ws_size,
                              hipStream_t stream) {
    const float* feat = (const float*)d_in[0];
    const float* fc_w = (const float*)d_in[1];
    const float* attn_l = (const float*)d_in[2];
    const float* attn_r = (const float*)d_in[3];
    const int* src = (const int*)d_in[4];
    const int* dst = (const int*)d_in[5];
    float* out = (float*)d_out;

    char* w = (char*)d_ws;
    unsigned short* fth = (unsigned short*)w;  w += (size_t)N_NODES * HD * 2;      // 25.6 MB (f16)
    unsigned short* fb = (unsigned short*)w;   w += (size_t)N_NODES * IN_F * 2;    // 25.6 MB (bf16 A)
    unsigned short* Bt = (unsigned short*)w;   w += (size_t)IN_F * HD * 2;         // 128 KB (bf16)
    float* el = (float*)w;       w += (size_t)N_NODES * NH * 4;                    // 800 KB
    float* er = (float*)w;       w += (size_t)N_NODES * NH * 4;                    // 800 KB
    unsigned short* hist16 = (unsigned short*)w;  w += (size_t)NHB * N_NODES * 2;  // 4.9 MB
    int* counts = (int*)w;       w += (size_t)N_NODES * 4;
    int* offs = (int*)w;         w += (size_t)N_NODES * 4;
    int* gcursor = (int*)w;      w += 256;
    unsigned short* erank16 = (unsigned short*)w; w += (size_t)N_EDGES * 2;        // 1.6 MB
    int* esrc = (int*)w;         w += (size_t)N_EDGES * 4;                          // 3.2 MB

    // pre: 49 hist + 128 Bt-cvt + 3125 feat-cvt blocks (one dispatch)
    k_pre<<<NHB + 128 + FCVB, 512, 0, stream>>>(fc_w, Bt, feat, fb, dst,
                                                hist16, erank16, gcursor);

    k_scan<<<(N_NODES + 511) / 512, 512, 0, stream>>>(hist16, counts, offs,
                                                      gcursor, N_NODES);

    // main: 196 gemm (A-LDS 64 KB, 2 blocks/CU) + 196 scatter, all co-resident
    k_main<<<GEMMB + SCATB, 512, 0, stream>>>(fb, Bt, fth, el, er, attn_l, attn_r,
                                              src, dst, hist16, offs, erank16,
                                              esrc, N_NODES);

    int agg_blocks = (N_NODES * 64 + 255) / 256;
    k_agg<<<agg_blocks, 256, 0, stream>>>(fth, el, er, offs, counts, esrc, out, N_NODES);
}